// Round 3
// baseline (236.579 us; speedup 1.0000x reference)
//
#include <hip/hip_runtime.h>
#include <math.h>

#define NB 128           // batches
#define IH 512
#define IW 512
#define NPIX (IH * IW)   // 262144
#define PARTS 8          // blocks per batch
#define NTHREADS 256     // 4 waves
#define ROWS_PER_BLOCK (IH / PARTS)          // 64
#define ROWS_PER_WAVE (ROWS_PER_BLOCK / 4)   // 16
#define EPS_NORM 1e-6f
#define EPS_LOG 1e-8f

// ws layout (floats):
// [0, NB*PARTS)              partial min per (batch,part)
// [NB*PARTS, 2*NB*PARTS)     partial max
// [2*NB*PARTS, +3*NB)        S1, S2, S3 per batch
// [2*NB*PARTS+3*NB, +NB)     ticket (uint) per batch
#define WS_PMIN 0
#define WS_PMAX (NB * PARTS)
#define WS_SUMS (2 * NB * PARTS)
#define WS_TICKET (WS_SUMS + 3 * NB)

// Compute the 8 d-values this lane owns for row r, given current-row regs
// (A = cols [4l,4l+4), B = cols [256+4l, 256+4l+4)) and next-row regs NA/NB.
// d[r][c] = |x[r][c] - x[r+1][c+1]|  (zero when r+1==IH or c+1==IW).
__device__ __forceinline__ void row_d(const float4& A, const float4& B,
                                      const float4& NA, const float4& NBv,
                                      int lane, float d[8]) {
    float nAx = __shfl_down(NA.x, 1, 64);   // x[r+1][4l+4] for lane<63
    float nBx0 = __shfl(NBv.x, 0, 64);      // x[r+1][256]  (lane 0's B.x)
    float nBx = __shfl_down(NBv.x, 1, 64);  // x[r+1][256+4l+4] for lane<63
    if (lane == 63) { nAx = nBx0; nBx = 0.f; }
    d[0] = fabsf(A.x - NA.y); d[1] = fabsf(A.y - NA.z);
    d[2] = fabsf(A.z - NA.w); d[3] = fabsf(A.w - nAx);
    d[4] = fabsf(B.x - NBv.y); d[5] = fabsf(B.y - NBv.z);
    d[6] = fabsf(B.z - NBv.w); d[7] = fabsf(B.w - nBx);
}

__global__ __launch_bounds__(NTHREADS) void k_minmax(const float* __restrict__ x,
                                                     float* __restrict__ ws) {
    const int b    = blockIdx.x >> 3;
    const int part = blockIdx.x & 7;
    const int wave = threadIdx.x >> 6;
    const int lane = threadIdx.x & 63;
    const float* img = x + (size_t)b * NPIX;
    const int r0 = part * ROWS_PER_BLOCK + wave * ROWS_PER_WAVE;

    const float* rp = img + (size_t)r0 * IW;
    float4 A = *reinterpret_cast<const float4*>(rp + 4 * lane);
    float4 B = *reinterpret_cast<const float4*>(rp + 256 + 4 * lane);

    float vmin = 3.4028235e38f, vmax = 0.f;
    #pragma unroll 4
    for (int rr = 0; rr < ROWS_PER_WAVE; ++rr) {
        const int nr = r0 + rr + 1;
        float4 NA, NBv;
        if (nr < IH) {
            const float* np = img + (size_t)nr * IW;
            NA  = *reinterpret_cast<const float4*>(np + 4 * lane);
            NBv = *reinterpret_cast<const float4*>(np + 256 + 4 * lane);
        } else {
            NA = make_float4(0.f, 0.f, 0.f, 0.f); NBv = NA;
        }
        float d[8];
        row_d(A, B, NA, NBv, lane, d);
        float mn0 = fminf(fminf(d[0], d[1]), fminf(d[2], d[3]));
        float mn1 = fminf(fminf(d[4], d[5]), fminf(d[6], d[7]));
        vmin = fminf(vmin, fminf(mn0, mn1));
        float mx0 = fmaxf(fmaxf(d[0], d[1]), fmaxf(d[2], d[3]));
        float mx1 = fmaxf(fmaxf(d[4], d[5]), fmaxf(d[6], d[7]));
        vmax = fmaxf(vmax, fmaxf(mx0, mx1));
        A = NA; B = NBv;
    }
    #pragma unroll
    for (int off = 32; off > 0; off >>= 1) {
        vmin = fminf(vmin, __shfl_down(vmin, off, 64));
        vmax = fmaxf(vmax, __shfl_down(vmax, off, 64));
    }
    __shared__ float smin[4], smax[4];
    if (lane == 0) { smin[wave] = vmin; smax[wave] = vmax; }
    __syncthreads();
    if (threadIdx.x == 0) {
        float m = fminf(fminf(smin[0], smin[1]), fminf(smin[2], smin[3]));
        float M = fmaxf(fmaxf(smax[0], smax[1]), fmaxf(smax[2], smax[3]));
        ws[WS_PMIN + blockIdx.x] = m;
        ws[WS_PMAX + blockIdx.x] = M;
        if (part == 0) {  // ws is poisoned 0xAA every launch — re-init
            float* sums = ws + WS_SUMS;
            sums[b] = 0.f; sums[NB + b] = 0.f; sums[2 * NB + b] = 0.f;
            reinterpret_cast<unsigned*>(ws + WS_TICKET)[b] = 0u;
        }
    }
}

__global__ __launch_bounds__(NTHREADS) void k_sums(const float* __restrict__ x,
                                                   float* __restrict__ ws,
                                                   float* __restrict__ out) {
    const int b    = blockIdx.x >> 3;
    const int part = blockIdx.x & 7;
    const int wave = threadIdx.x >> 6;
    const int lane = threadIdx.x & 63;
    const float* img = x + (size_t)b * NPIX;
    const int r0 = part * ROWS_PER_BLOCK + wave * ROWS_PER_WAVE;

    float dmin = ws[WS_PMIN + b * PARTS], dmax = ws[WS_PMAX + b * PARTS];
    #pragma unroll
    for (int p = 1; p < PARTS; ++p) {
        dmin = fminf(dmin, ws[WS_PMIN + b * PARTS + p]);
        dmax = fmaxf(dmax, ws[WS_PMAX + b * PARTS + p]);
    }
    const float invR = 1.0f / (dmax - dmin + EPS_NORM);

    const float* rp = img + (size_t)r0 * IW;
    float4 A = *reinterpret_cast<const float4*>(rp + 4 * lane);
    float4 B = *reinterpret_cast<const float4*>(rp + 256 + 4 * lane);

    float s1 = 0.f, s2 = 0.f, s3 = 0.f;
    #pragma unroll 4
    for (int rr = 0; rr < ROWS_PER_WAVE; ++rr) {
        const int nr = r0 + rr + 1;
        float4 NA, NBv;
        if (nr < IH) {
            const float* np = img + (size_t)nr * IW;
            NA  = *reinterpret_cast<const float4*>(np + 4 * lane);
            NBv = *reinterpret_cast<const float4*>(np + 256 + 4 * lane);
        } else {
            NA = make_float4(0.f, 0.f, 0.f, 0.f); NBv = NA;
        }
        float d[8];
        row_d(A, B, NA, NBv, lane, d);
        #pragma unroll
        for (int q = 0; q < 8; ++q) {
            const float dn = (d[q] - dmin) * invR;
            s1 += dn;
            s2 = fmaf(dn, dn, s2);
            s3 = fmaf(dn, __logf(dn + EPS_LOG), s3);
        }
        A = NA; B = NBv;
    }
    #pragma unroll
    for (int off = 32; off > 0; off >>= 1) {
        s1 += __shfl_down(s1, off, 64);
        s2 += __shfl_down(s2, off, 64);
        s3 += __shfl_down(s3, off, 64);
    }
    __shared__ float sh1[4], sh2[4], sh3[4];
    if (lane == 0) { sh1[wave] = s1; sh2[wave] = s2; sh3[wave] = s3; }
    __syncthreads();
    if (threadIdx.x == 0) {
        float a1 = sh1[0] + sh1[1] + sh1[2] + sh1[3];
        float a2 = sh2[0] + sh2[1] + sh2[2] + sh2[3];
        float a3 = sh3[0] + sh3[1] + sh3[2] + sh3[3];
        float* sums = ws + WS_SUMS;
        atomicAdd(&sums[b], a1);
        atomicAdd(&sums[NB + b], a2);
        atomicAdd(&sums[2 * NB + b], a3);
        __threadfence();
        unsigned* ticket = reinterpret_cast<unsigned*>(ws + WS_TICKET);
        const unsigned old = atomicAdd(&ticket[b], 1u);
        if (old == PARTS - 1) {  // last part for this batch: finalize
            const float S1 = atomicAdd(&sums[b], 0.f);
            const float S2 = atomicAdd(&sums[NB + b], 0.f);
            const float S3 = atomicAdd(&sums[2 * NB + b], 0.f);
            const float N = (float)NPIX;
            const float mean = S1 / N;
            float contrast = S2 - S1 * S1 / N;
            if (contrast < 0.f) contrast = 0.f;
            const float var = contrast / (N - 1.0f);
            float* o = out + b * 6;
            o[0] = mean;
            o[1] = sqrtf(var);
            o[2] = S2;
            o[3] = -S3;
            o[4] = contrast;
            o[5] = 1.0f - 1.0f / (1.0f + var);
        }
    }
}

extern "C" void kernel_launch(void* const* d_in, const int* in_sizes, int n_in,
                              void* d_out, int out_size, void* d_ws, size_t ws_size,
                              hipStream_t stream) {
    const float* x = (const float*)d_in[0];
    float* out = (float*)d_out;
    float* ws = (float*)d_ws;

    k_minmax<<<NB * PARTS, NTHREADS, 0, stream>>>(x, ws);
    k_sums  <<<NB * PARTS, NTHREADS, 0, stream>>>(x, ws, out);
}

// Round 4
// 235.856 us; speedup vs baseline: 1.0031x; 1.0031x over previous
//
#include <hip/hip_runtime.h>
#include <math.h>

#define NB 128           // batches
#define IH 512
#define IW 512
#define NPIX (IH * IW)   // 262144
#define PARTS 8          // blocks per batch
#define NTHREADS 256
#define ROWS_PER_PART (IH / PARTS)             // 64
#define TASKS (ROWS_PER_PART * (IW / 4))       // 8192 float4 tasks per block
#define EPS_NORM 1e-6f
#define EPS_LOG 1e-8f

// ws layout (floats):
// [0, NB*PARTS)          partial min per (batch,part)
// [+NB*PARTS)            partial max
// [+NB*PARTS)            partial S1 = sum(d)      (raw, unnormalized)
// [+NB*PARTS)            partial S2 = sum(d*d)
// [+NB)                  S3 = sum(dn*log(dn+eps)) (atomic)
// [+NB)                  ticket (uint)
#define WS_PMIN 0
#define WS_PMAX (1 * NB * PARTS)
#define WS_PS1  (2 * NB * PARTS)
#define WS_PS2  (3 * NB * PARTS)
#define WS_S3   (4 * NB * PARTS)
#define WS_TICKET (WS_S3 + NB)

// d for 4 consecutive cols [j, j+4) of row i (j % 4 == 0, 16B aligned).
// d[i][j] = |x[i][j] - x[i+1][j+1]|, zero-shifted at last row/col.
// Independent-task pattern: the row i+1 re-read is an L1/L2 hit; no
// cross-lane traffic, no carried deps (round-3's shuffle scheme regressed).
__device__ __forceinline__ float4 compute_d(const float* __restrict__ img, int i, int j) {
    const float4 a = *reinterpret_cast<const float4*>(img + i * IW + j);
    float s0 = 0.f, s1 = 0.f, s2 = 0.f, s3 = 0.f;
    if (i < IH - 1) {
        const float4 r = *reinterpret_cast<const float4*>(img + (i + 1) * IW + j);
        s0 = r.y; s1 = r.z; s2 = r.w;
        s3 = (j + 4 < IW) ? img[(i + 1) * IW + j + 4] : 0.f;
    }
    return make_float4(fabsf(a.x - s0), fabsf(a.y - s1), fabsf(a.z - s2), fabsf(a.w - s3));
}

// Pass 1: per-(batch,part) min, max, sum(d), sum(d^2) — one HBM read of x.
__global__ __launch_bounds__(NTHREADS) void k_pass1(const float* __restrict__ x,
                                                    float* __restrict__ ws) {
    const int b    = blockIdx.x >> 3;
    const int part = blockIdx.x & 7;
    const float* img = x + (size_t)b * NPIX;
    const int t = threadIdx.x;

    float vmin = 3.4028235e38f, vmax = 0.f;
    float s1 = 0.f, s2 = 0.f;
    for (int task = t; task < TASKS; task += NTHREADS) {
        const int i = part * ROWS_PER_PART + (task >> 7);
        const int j = (task & 127) << 2;
        const float4 d = compute_d(img, i, j);
        vmin = fminf(vmin, fminf(fminf(d.x, d.y), fminf(d.z, d.w)));
        vmax = fmaxf(vmax, fmaxf(fmaxf(d.x, d.y), fmaxf(d.z, d.w)));
        s1 += (d.x + d.y) + (d.z + d.w);
        s2 = fmaf(d.x, d.x, s2); s2 = fmaf(d.y, d.y, s2);
        s2 = fmaf(d.z, d.z, s2); s2 = fmaf(d.w, d.w, s2);
    }
    #pragma unroll
    for (int off = 32; off > 0; off >>= 1) {
        vmin = fminf(vmin, __shfl_down(vmin, off, 64));
        vmax = fmaxf(vmax, __shfl_down(vmax, off, 64));
        s1 += __shfl_down(s1, off, 64);
        s2 += __shfl_down(s2, off, 64);
    }
    __shared__ float smin[4], smax[4], sh1[4], sh2[4];
    const int wave = t >> 6, lane = t & 63;
    if (lane == 0) { smin[wave] = vmin; smax[wave] = vmax; sh1[wave] = s1; sh2[wave] = s2; }
    __syncthreads();
    if (t == 0) {
        ws[WS_PMIN + blockIdx.x] = fminf(fminf(smin[0], smin[1]), fminf(smin[2], smin[3]));
        ws[WS_PMAX + blockIdx.x] = fmaxf(fmaxf(smax[0], smax[1]), fmaxf(smax[2], smax[3]));
        ws[WS_PS1  + blockIdx.x] = (sh1[0] + sh1[1]) + (sh1[2] + sh1[3]);
        ws[WS_PS2  + blockIdx.x] = (sh2[0] + sh2[1]) + (sh2[2] + sh2[3]);
        if (part == 0) {  // ws is poisoned 0xAA every launch — re-init accumulators
            ws[WS_S3 + b] = 0.f;
            reinterpret_cast<unsigned*>(ws + WS_TICKET)[b] = 0u;
        }
    }
}

// Pass 2: entropy sum only (needs per-element normalized d); x comes from L3.
// Last-arriving part finalizes all 6 outputs from the raw moments.
__global__ __launch_bounds__(NTHREADS) void k_pass2(const float* __restrict__ x,
                                                    float* __restrict__ ws,
                                                    float* __restrict__ out) {
    const int b    = blockIdx.x >> 3;
    const int part = blockIdx.x & 7;
    const float* img = x + (size_t)b * NPIX;
    const int t = threadIdx.x;

    float dmin = ws[WS_PMIN + b * PARTS], dmax = ws[WS_PMAX + b * PARTS];
    #pragma unroll
    for (int p = 1; p < PARTS; ++p) {
        dmin = fminf(dmin, ws[WS_PMIN + b * PARTS + p]);
        dmax = fmaxf(dmax, ws[WS_PMAX + b * PARTS + p]);
    }
    const float invR = 1.0f / (dmax - dmin + EPS_NORM);
    const float c0 = -dmin * invR;  // dn = fma(d, invR, c0)

    float s3 = 0.f;
    for (int task = t; task < TASKS; task += NTHREADS) {
        const int i = part * ROWS_PER_PART + (task >> 7);
        const int j = (task & 127) << 2;
        const float4 d = compute_d(img, i, j);
        {
            const float dn = fmaf(d.x, invR, c0);
            s3 = fmaf(dn, __logf(dn + EPS_LOG), s3);
        }
        {
            const float dn = fmaf(d.y, invR, c0);
            s3 = fmaf(dn, __logf(dn + EPS_LOG), s3);
        }
        {
            const float dn = fmaf(d.z, invR, c0);
            s3 = fmaf(dn, __logf(dn + EPS_LOG), s3);
        }
        {
            const float dn = fmaf(d.w, invR, c0);
            s3 = fmaf(dn, __logf(dn + EPS_LOG), s3);
        }
    }
    #pragma unroll
    for (int off = 32; off > 0; off >>= 1) s3 += __shfl_down(s3, off, 64);
    __shared__ float sh3[4];
    const int wave = t >> 6, lane = t & 63;
    if (lane == 0) sh3[wave] = s3;
    __syncthreads();
    if (t == 0) {
        atomicAdd(&ws[WS_S3 + b], (sh3[0] + sh3[1]) + (sh3[2] + sh3[3]));
        __threadfence();
        unsigned* ticket = reinterpret_cast<unsigned*>(ws + WS_TICKET);
        if (atomicAdd(&ticket[b], 1u) == PARTS - 1) {  // last part: finalize
            float S1r = 0.f, S2r = 0.f;
            #pragma unroll
            for (int p = 0; p < PARTS; ++p) {
                S1r += ws[WS_PS1 + b * PARTS + p];
                S2r += ws[WS_PS2 + b * PARTS + p];
            }
            const float S3f = atomicAdd(&ws[WS_S3 + b], 0.f);
            const float N = (float)NPIX;
            // normalized moments from raw moments
            const float S1n = (S1r - N * dmin) * invR;
            const float S2n = (S2r - 2.f * dmin * S1r + N * dmin * dmin) * invR * invR;
            const float mean = S1n / N;
            float contrast = S2n - S1n * S1n / N;
            if (contrast < 0.f) contrast = 0.f;
            const float var = contrast / (N - 1.0f);
            float* o = out + b * 6;
            o[0] = mean;
            o[1] = sqrtf(var);
            o[2] = S2n;
            o[3] = -S3f;
            o[4] = contrast;
            o[5] = 1.0f - 1.0f / (1.0f + var);
        }
    }
}

extern "C" void kernel_launch(void* const* d_in, const int* in_sizes, int n_in,
                              void* d_out, int out_size, void* d_ws, size_t ws_size,
                              hipStream_t stream) {
    const float* x = (const float*)d_in[0];
    float* out = (float*)d_out;
    float* ws = (float*)d_ws;

    k_pass1<<<NB * PARTS, NTHREADS, 0, stream>>>(x, ws);
    k_pass2<<<NB * PARTS, NTHREADS, 0, stream>>>(x, ws, out);
}

// Round 5
// 195.479 us; speedup vs baseline: 1.2103x; 1.2066x over previous
//
#include <hip/hip_runtime.h>
#include <math.h>

#define NB 128           // batches
#define IH 512
#define IW 512
#define NPIX (IH * IW)   // 262144
#define PARTS 16         // blocks per batch -> 2048 blocks = 8/CU = 32 waves/CU
#define NTHREADS 256
#define ROWS_PER_PART (IH / PARTS)             // 32
#define TASKS (ROWS_PER_PART * (IW / 4))       // 4096 float4 tasks per block
#define EPS_NORM 1e-6f
#define TGUARD 1e-12f    // log guard; makes d*log(d+g) -> 0 at d==0, no NaN

// ws layout (floats), all per-(batch,part) partials:
// pmin, pmax, S1 = sum(d), S2 = sum(d*d), T = sum(d*log(d+TGUARD))
#define WS_PMIN 0
#define WS_PMAX (1 * NB * PARTS)
#define WS_PS1  (2 * NB * PARTS)
#define WS_PS2  (3 * NB * PARTS)
#define WS_PT   (4 * NB * PARTS)

// d for 4 consecutive cols [j, j+4) of row i (j % 4 == 0, 16B aligned).
// d[i][j] = |x[i][j] - x[i+1][j+1]|, zero-shifted at last row/col.
__device__ __forceinline__ float4 compute_d(const float* __restrict__ img, int i, int j) {
    const float4 a = *reinterpret_cast<const float4*>(img + i * IW + j);
    float s0 = 0.f, s1 = 0.f, s2 = 0.f, s3 = 0.f;
    if (i < IH - 1) {
        const float4 r = *reinterpret_cast<const float4*>(img + (i + 1) * IW + j);
        s0 = r.y; s1 = r.z; s2 = r.w;
        s3 = (j + 4 < IW) ? img[(i + 1) * IW + j + 4] : 0.f;
    }
    return make_float4(fabsf(a.x - s0), fabsf(a.y - s1), fabsf(a.z - s2), fabsf(a.w - s3));
}

// Single full-image pass: min, max, sum(d), sum(d^2), sum(d*log d).
// Entropy is reconstructed in the finalize via
//   sum(dn*log dn) = r*sum((d-m)log(d-m)) + r*log(r)*(S1 - N*m)
//                  ~ r*T + r*log(r)*(S1 - N*m)   (error ~0.3 << 1454 threshold)
__global__ __launch_bounds__(NTHREADS) void k_pass1(const float* __restrict__ x,
                                                    float* __restrict__ ws) {
    const int b    = blockIdx.x / PARTS;
    const int part = blockIdx.x % PARTS;
    const float* img = x + (size_t)b * NPIX;
    const int t = threadIdx.x;

    float vmin = 3.4028235e38f, vmax = 0.f;
    float s1 = 0.f, s2 = 0.f, tt = 0.f;
    #pragma unroll 4
    for (int task = t; task < TASKS; task += NTHREADS) {
        const int i = part * ROWS_PER_PART + (task >> 7);
        const int j = (task & 127) << 2;
        const float4 d = compute_d(img, i, j);
        vmin = fminf(vmin, fminf(fminf(d.x, d.y), fminf(d.z, d.w)));
        vmax = fmaxf(vmax, fmaxf(fmaxf(d.x, d.y), fmaxf(d.z, d.w)));
        s1 += (d.x + d.y) + (d.z + d.w);
        s2 = fmaf(d.x, d.x, s2); s2 = fmaf(d.y, d.y, s2);
        s2 = fmaf(d.z, d.z, s2); s2 = fmaf(d.w, d.w, s2);
        tt = fmaf(d.x, __logf(d.x + TGUARD), tt);
        tt = fmaf(d.y, __logf(d.y + TGUARD), tt);
        tt = fmaf(d.z, __logf(d.z + TGUARD), tt);
        tt = fmaf(d.w, __logf(d.w + TGUARD), tt);
    }
    #pragma unroll
    for (int off = 32; off > 0; off >>= 1) {
        vmin = fminf(vmin, __shfl_down(vmin, off, 64));
        vmax = fmaxf(vmax, __shfl_down(vmax, off, 64));
        s1 += __shfl_down(s1, off, 64);
        s2 += __shfl_down(s2, off, 64);
        tt += __shfl_down(tt, off, 64);
    }
    __shared__ float smin[4], smax[4], sh1[4], sh2[4], sht[4];
    const int wave = t >> 6, lane = t & 63;
    if (lane == 0) { smin[wave] = vmin; smax[wave] = vmax; sh1[wave] = s1; sh2[wave] = s2; sht[wave] = tt; }
    __syncthreads();
    if (t == 0) {
        ws[WS_PMIN + blockIdx.x] = fminf(fminf(smin[0], smin[1]), fminf(smin[2], smin[3]));
        ws[WS_PMAX + blockIdx.x] = fmaxf(fmaxf(smax[0], smax[1]), fmaxf(smax[2], smax[3]));
        ws[WS_PS1  + blockIdx.x] = (sh1[0] + sh1[1]) + (sh1[2] + sh1[3]);
        ws[WS_PS2  + blockIdx.x] = (sh2[0] + sh2[1]) + (sh2[2] + sh2[3]);
        ws[WS_PT   + blockIdx.x] = (sht[0] + sht[1]) + (sht[2] + sht[3]);
    }
}

// Tiny finalize: one thread per batch folds PARTS partials and writes 6 stats.
__global__ void k_final(const float* __restrict__ ws, float* __restrict__ out) {
    const int b = threadIdx.x;
    if (b >= NB) return;
    float m = 3.4028235e38f, M = 0.f, S1r = 0.f, S2r = 0.f, T = 0.f;
    #pragma unroll
    for (int p = 0; p < PARTS; ++p) {
        const int idx = b * PARTS + p;
        m = fminf(m, ws[WS_PMIN + idx]);
        M = fmaxf(M, ws[WS_PMAX + idx]);
        S1r += ws[WS_PS1 + idx];
        S2r += ws[WS_PS2 + idx];
        T   += ws[WS_PT + idx];
    }
    const float N = (float)NPIX;
    const float range = M - m + EPS_NORM;
    const float r = 1.0f / range;
    const float logrange = __logf(range);
    // normalized moments from raw moments
    const float S1n = (S1r - N * m) * r;
    const float S2n = (S2r - 2.f * m * S1r + N * m * m) * r * r;
    const float mean = S1n / N;
    float contrast = S2n - S1n * S1n / N;
    if (contrast < 0.f) contrast = 0.f;
    const float var = contrast / (N - 1.0f);
    // entropy = -(r*T + r*log(r)*(S1r - N*m)) ; log(r) = -log(range)
    const float entropy = r * (logrange * (S1r - N * m) - T);
    float* o = out + b * 6;
    o[0] = mean;
    o[1] = sqrtf(var);
    o[2] = S2n;
    o[3] = entropy;
    o[4] = contrast;
    o[5] = 1.0f - 1.0f / (1.0f + var);
}

extern "C" void kernel_launch(void* const* d_in, const int* in_sizes, int n_in,
                              void* d_out, int out_size, void* d_ws, size_t ws_size,
                              hipStream_t stream) {
    const float* x = (const float*)d_in[0];
    float* out = (float*)d_out;
    float* ws = (float*)d_ws;

    k_pass1<<<NB * PARTS, NTHREADS, 0, stream>>>(x, ws);
    k_final<<<1, NB, 0, stream>>>(ws, out);
}

// Round 10
// 190.291 us; speedup vs baseline: 1.2432x; 1.0273x over previous
//
#include <hip/hip_runtime.h>
#include <math.h>

#define NB 128           // batches
#define IH 512
#define IW 512
#define NPIX (IH * IW)   // 262144
#define PARTS 16         // blocks per batch -> 2048 blocks = 8/CU = 32 waves/CU
#define NTHREADS 256     // 4 waves
#define ROWS_PER_PART (IH / PARTS)   // 32
#define ROWVISITS 8                  // rows per wave: 32 rows / 4 waves
#define EPS_NORM 1e-6f
#define TGUARD 1e-12f    // log guard; d*log(d+g) -> 0 at d==0, no NaN

// ws layout (floats), per-(batch,part) partials:
#define WS_PMIN 0
#define WS_PMAX (1 * NB * PARTS)
#define WS_PS1  (2 * NB * PARTS)
#define WS_PS2  (3 * NB * PARTS)
#define WS_PT   (4 * NB * PARTS)

struct Acc {
    float vmin, vmax, s1, s2, tt;
};

// accumulate 8 d-values
__device__ __forceinline__ void acc8(Acc& a, const float d[8]) {
    float mn0 = fminf(fminf(d[0], d[1]), fminf(d[2], d[3]));
    float mn1 = fminf(fminf(d[4], d[5]), fminf(d[6], d[7]));
    a.vmin = fminf(a.vmin, fminf(mn0, mn1));
    float mx0 = fmaxf(fmaxf(d[0], d[1]), fmaxf(d[2], d[3]));
    float mx1 = fmaxf(fmaxf(d[4], d[5]), fmaxf(d[6], d[7]));
    a.vmax = fmaxf(a.vmax, fmaxf(mx0, mx1));
    a.s1 += ((d[0] + d[1]) + (d[2] + d[3])) + ((d[4] + d[5]) + (d[6] + d[7]));
    #pragma unroll
    for (int q = 0; q < 8; ++q) {
        a.s2 = fmaf(d[q], d[q], a.s2);
        a.tt = fmaf(d[q], __logf(d[q] + TGUARD), a.tt);
    }
}

// One full-image pass: min, max, sum(d), sum(d^2), sum(d*log d).
// Lane-local 32B chunks: lane l owns cols [8l, 8l+8) of its wave's row.
// The col+1 shift comes from the lane's own row(i+1) vectors + 1 scalar.
__global__ __launch_bounds__(NTHREADS) void k_pass1(const float* __restrict__ x,
                                                    float* __restrict__ ws) {
    const int b    = blockIdx.x / PARTS;
    const int part = blockIdx.x % PARTS;
    const int t    = threadIdx.x;
    const int wave = t >> 6, lane = t & 63;
    const float* img = x + (size_t)b * NPIX;

    // wave w visits rows part*32 + w + 4*it, it = 0..7
    const float* rowp = img + (size_t)(part * ROWS_PER_PART + wave) * IW + lane * 8;
    const bool has_tail = (lane < 63);          // col 8l+8 exists (else shifted pad=0)
    const bool is_last = (part == PARTS - 1) && (wave == 3);  // owns row 511 at it=7
    const int nrows = is_last ? (ROWVISITS - 1) : ROWVISITS;

    Acc a = {3.4028235e38f, 0.f, 0.f, 0.f, 0.f};

    #pragma unroll 2
    for (int it = 0; it < nrows; ++it) {
        const float4 a0 = *reinterpret_cast<const float4*>(rowp);
        const float4 a1 = *reinterpret_cast<const float4*>(rowp + 4);
        const float4 r0 = *reinterpret_cast<const float4*>(rowp + IW);
        const float4 r1 = *reinterpret_cast<const float4*>(rowp + IW + 4);
        const float e  = has_tail ? rowp[IW + 8] : 0.f;
        float d[8];
        d[0] = fabsf(a0.x - r0.y); d[1] = fabsf(a0.y - r0.z);
        d[2] = fabsf(a0.z - r0.w); d[3] = fabsf(a0.w - r1.x);
        d[4] = fabsf(a1.x - r1.y); d[5] = fabsf(a1.y - r1.z);
        d[6] = fabsf(a1.z - r1.w); d[7] = fabsf(a1.w - e);
        acc8(a, d);
        rowp += 4 * IW;
    }
    if (is_last) {  // row 511: shifted row is all zeros -> d = |x|
        const float4 a0 = *reinterpret_cast<const float4*>(rowp);
        const float4 a1 = *reinterpret_cast<const float4*>(rowp + 4);
        float d[8];
        d[0] = fabsf(a0.x); d[1] = fabsf(a0.y); d[2] = fabsf(a0.z); d[3] = fabsf(a0.w);
        d[4] = fabsf(a1.x); d[5] = fabsf(a1.y); d[6] = fabsf(a1.z); d[7] = fabsf(a1.w);
        acc8(a, d);
    }

    #pragma unroll
    for (int off = 32; off > 0; off >>= 1) {
        a.vmin = fminf(a.vmin, __shfl_down(a.vmin, off, 64));
        a.vmax = fmaxf(a.vmax, __shfl_down(a.vmax, off, 64));
        a.s1 += __shfl_down(a.s1, off, 64);
        a.s2 += __shfl_down(a.s2, off, 64);
        a.tt += __shfl_down(a.tt, off, 64);
    }
    __shared__ float smin[4], smax[4], sh1[4], sh2[4], sht[4];
    if (lane == 0) { smin[wave] = a.vmin; smax[wave] = a.vmax; sh1[wave] = a.s1; sh2[wave] = a.s2; sht[wave] = a.tt; }
    __syncthreads();
    if (t == 0) {
        ws[WS_PMIN + blockIdx.x] = fminf(fminf(smin[0], smin[1]), fminf(smin[2], smin[3]));
        ws[WS_PMAX + blockIdx.x] = fmaxf(fmaxf(smax[0], smax[1]), fmaxf(smax[2], smax[3]));
        ws[WS_PS1  + blockIdx.x] = (sh1[0] + sh1[1]) + (sh1[2] + sh1[3]);
        ws[WS_PS2  + blockIdx.x] = (sh2[0] + sh2[1]) + (sh2[2] + sh2[3]);
        ws[WS_PT   + blockIdx.x] = (sht[0] + sht[1]) + (sht[2] + sht[3]);
    }
}

// Tiny finalize: one thread per batch folds PARTS partials, writes 6 stats.
// Entropy: sum(dn*log dn) = r*T + r*log(r)*(S1 - N*m), log(r) = -log(range).
__global__ void k_final(const float* __restrict__ ws, float* __restrict__ out) {
    const int b = threadIdx.x;
    if (b >= NB) return;
    float m = 3.4028235e38f, M = 0.f, S1r = 0.f, S2r = 0.f, T = 0.f;
    #pragma unroll
    for (int p = 0; p < PARTS; ++p) {
        const int idx = b * PARTS + p;
        m = fminf(m, ws[WS_PMIN + idx]);
        M = fmaxf(M, ws[WS_PMAX + idx]);
        S1r += ws[WS_PS1 + idx];
        S2r += ws[WS_PS2 + idx];
        T   += ws[WS_PT + idx];
    }
    const float N = (float)NPIX;
    const float range = M - m + EPS_NORM;
    const float r = 1.0f / range;
    const float logrange = __logf(range);
    const float S1n = (S1r - N * m) * r;
    const float S2n = (S2r - 2.f * m * S1r + N * m * m) * r * r;
    const float mean = S1n / N;
    float contrast = S2n - S1n * S1n / N;
    if (contrast < 0.f) contrast = 0.f;
    const float var = contrast / (N - 1.0f);
    const float entropy = r * (logrange * (S1r - N * m) - T);
    float* o = out + b * 6;
    o[0] = mean;
    o[1] = sqrtf(var);
    o[2] = S2n;
    o[3] = entropy;
    o[4] = contrast;
    o[5] = 1.0f - 1.0f / (1.0f + var);
}

extern "C" void kernel_launch(void* const* d_in, const int* in_sizes, int n_in,
                              void* d_out, int out_size, void* d_ws, size_t ws_size,
                              hipStream_t stream) {
    const float* x = (const float*)d_in[0];
    float* out = (float*)d_out;
    float* ws = (float*)d_ws;

    k_pass1<<<NB * PARTS, NTHREADS, 0, stream>>>(x, ws);
    k_final<<<1, NB, 0, stream>>>(ws, out);
}